// Round 12
// baseline (724.401 us; speedup 1.0000x reference)
//
#include <hip/hip_runtime.h>
#include <hip/hip_fp16.h>
#include <hip/hip_cooperative_groups.h>

namespace cg = cooperative_groups;

// LSTM_48850958024796 — R12: single cooperative mega-kernel. Phases:
//   P0 pack weights -> P1 l0 scan (256 blk-roles) -> P2 gemm_xg -> P3 l1 scan.
// grid.sync() + __threadfence() between phases (device-scope fence required:
// per-XCD L2s are not cross-coherent; kernel boundaries used to provide this).
// Phase internals identical to R11 (proven: 8-row spread, exec-safe
// ds_swizzle(0x17), register-resident weights, register-direct xg prefetch).
// Scan math (R3): gates^T = W(A) @ [h|x|1]^T(B), cols gate-interleaved
// (n'=4j+gate): lane(q,l16) of tile mt holds gates i,f,g,o of (m=l16&7,
// j=mt*4+q); lanes l16>=8 take tile B's gates from lane&~8; c in VGPRs.

typedef __attribute__((ext_vector_type(8))) short bf16x8;
typedef __attribute__((ext_vector_type(4))) float f32x4;

constexpr int Bsz = 1024, Tt = 128, IN_ = 5, H = 100, G = 400, D1 = 200;
constexpr int NP = 512;   // packed gate cols (32 tiles of 16)
constexpr int NT = 25;    // real tiles (400/16)
constexpr int MB = 8;     // batch rows per block (scans)

__device__ __forceinline__ float sigm(float x)   { return 1.f / (1.f + __expf(-x)); }
__device__ __forceinline__ float tanhf_(float x) { return 1.f - 2.f / (__expf(2.f * x) + 1.f); }
__device__ __forceinline__ unsigned short f2bf(float f) {
  unsigned u = __float_as_uint(f);
  u += 0x7fff + ((u >> 16) & 1);
  return (unsigned short)(u >> 16);
}
// every lane receives the value held by lane (lane & ~8); unconditional.
__device__ __forceinline__ float partner8(float v) {
  return __uint_as_float(
      (unsigned)__builtin_amdgcn_ds_swizzle((int)__float_as_uint(v), 0x17));
}
// LDS-only barrier (no vmcnt drain); loads are vmcnt-guarded at use.
__device__ __forceinline__ void barrier_nv() {
  asm volatile("s_waitcnt lgkmcnt(0)\n\ts_barrier" ::: "memory");
}

// packed col n' (0..511): j=n'>>2, gate=n'&3, src row n = gate*100+j; j>=100->0
__device__ __forceinline__ void pack_body(
    const float* wA, int KA, const float* wB, int KB, int kbo,
    const float* b1, const float* b2, int bias_k,
    unsigned short* dst, int idx) {
  int jj = idx & 7, rest = idx >> 3;
  int np_ = rest % NP, g = rest / NP;
  int j = np_ >> 2, gate = np_ & 3;
  int k = g * 8 + jj;
  float v = 0.f;
  if (j < H) {
    int n = gate * H + j;
    if (k < KA) v = wA[n * KA + k];
    else if (KB > 0 && k >= kbo && k < kbo + KB) v = wB[n * KB + (k - kbo)];
    else if (k == bias_k) v = b1[n] + b2[n];
  }
  dst[idx] = f2bf(v);
}

constexpr int SMEM_BYTES = 28672;  // max over phases (P2 B_s 28*64*8*2)

__global__ __launch_bounds__(1024, 4) void lstm_mega(
    const float* __restrict__ x,
    const float* __restrict__ w_ih_l0f, const float* __restrict__ w_hh_l0f,
    const float* __restrict__ b_ih_l0f, const float* __restrict__ b_hh_l0f,
    const float* __restrict__ w_ih_l0b, const float* __restrict__ w_hh_l0b,
    const float* __restrict__ b_ih_l0b, const float* __restrict__ b_hh_l0b,
    const float* __restrict__ w_ih_l1f, const float* __restrict__ w_hh_l1f,
    const float* __restrict__ b_ih_l1f, const float* __restrict__ b_hh_l1f,
    const float* __restrict__ w_ih_l1b,
    const float* __restrict__ b_ih_l1b, const float* __restrict__ b_hh_l1b,
    const float* __restrict__ fc_w, const float* __restrict__ fc_b,
    unsigned short* __restrict__ pk0f, unsigned short* __restrict__ pk0b,
    unsigned short* __restrict__ pkhh, unsigned short* __restrict__ pkxg,
    unsigned short* __restrict__ pk1b,
    unsigned short* __restrict__ h0fT, unsigned short* __restrict__ h0bT,
    __half* __restrict__ xg, float* __restrict__ out) {
  __shared__ __align__(16) char smem[SMEM_BYTES];
  cg::grid_group grid = cg::this_grid();

  const int bid = blockIdx.x;                // 0..255
  const int tid = threadIdx.x;
  const int lane = tid & 63, w = tid >> 6;   // 16 waves
  const int q = lane >> 4, l16 = lane & 15;

  // ================= P0: pack all weight tensors =================
  {
    // segments: pk0f 65536 | pk0b 65536 | pkhh 65536 | pkxg 114688 | pk1b 114688
    for (int idx = bid * 1024 + tid; idx < 425984; idx += 262144) {
      if (idx < 65536)
        pack_body(w_hh_l0f, 100, w_ih_l0f, 5, 100, b_ih_l0f, b_hh_l0f, 105, pk0f, idx);
      else if (idx < 131072)
        pack_body(w_hh_l0b, 100, w_ih_l0b, 5, 100, b_ih_l0b, b_hh_l0b, 105, pk0b, idx - 65536);
      else if (idx < 196608)
        pack_body(w_hh_l1f, 100, nullptr, 0, 0, b_ih_l1f, b_hh_l1f, -1, pkhh, idx - 131072);
      else if (idx < 311296)
        pack_body(w_ih_l1f, 200, nullptr, 0, 0, b_ih_l1f, b_hh_l1f, 200, pkxg, idx - 196608);
      else
        pack_body(w_ih_l1b, 200, nullptr, 0, 0, b_ih_l1b, b_hh_l1b, 200, pk1b, idx - 311296);
    }
  }
  __threadfence();
  grid.sync();

  // ================= P1: layer-0 scan (all 256 blocks) =================
  {
    auto A_s = (short(*)[16][16][8])smem;  // [2][16][16][8]
    const int dir = bid >> 7;
    const int b0 = (bid & 127) * MB;
    const unsigned short* pk = dir ? pk0b : pk0f;
    unsigned short* hT = dir ? h0bT : h0fT;

    for (int i = tid; i < 2 * 16 * 16 * 8; i += 1024) ((short*)A_s)[i] = 0;

    const int mtA = w, mtB = w + 16;
    const bool bvalid = (mtB < NT);
    bf16x8 wfA[4], wfB[4];
#pragma unroll
    for (int kt = 0; kt < 4; ++kt) {
      wfA[kt] = *(const bf16x8*)(pk + ((size_t)(kt * 4 + q) * NP + mtA * 16 + l16) * 8);
      wfB[kt] = *(const bf16x8*)(pk + ((size_t)(kt * 4 + q) * NP + mtB * 16 + l16) * 8);
    }
    float c = 0.f;
    const bool up = (l16 >= 8);
    const int mm = l16 & 7;
    const int j = (up ? mtB : mtA) * 4 + q;
    const bool valid = up ? bvalid : true;
    const int xm = tid / IN_, xe = tid - xm * IN_;              // tid<40
    const int sm = tid / 25, sj = (tid - (tid / 25) * 25) * 4;  // tid<200
    const float* xp = x + ((size_t)(b0 + xm) * Tt + (dir ? Tt - 2 : 1)) * IN_ + xe;
    const int xstride = dir ? -IN_ : IN_;
    unsigned short* hp =
        hT + ((size_t)(dir ? Tt - 1 : 0) * Bsz + b0 + sm) * H + sj;
    const int hstride = dir ? -(Bsz * H) : (Bsz * H);
    __syncthreads();
    if (tid < 16) {  // bias-one col k=105 (kg13,jj1), both bufs
      A_s[0][13][tid][1] = (short)f2bf(1.f);
      A_s[1][13][tid][1] = (short)f2bf(1.f);
    }
    if (tid < MB * IN_) {  // x(t_first) -> buf0
      int t0 = dir ? (Tt - 1) : 0;
      int k = 100 + xe;
      A_s[0][k >> 3][xm][k & 7] =
          (short)f2bf(x[((size_t)(b0 + xm) * Tt + t0) * IN_ + xe]);
    }
    __syncthreads();

    int p = 0;
    for (int step = 0; step < Tt; ++step) {
      if (step > 0 && tid < 200) {
        uint2 hv = *(const uint2*)&A_s[p][sj >> 3][sm][sj & 7];
        *(uint2*)hp = hv;
        hp += hstride;
      }
      float xn = 0.f;
      const bool do_x = (tid < MB * IN_) && (step < Tt - 1);
      if (do_x) { xn = *xp; xp += xstride; }
      bf16x8 hfrag[4];
#pragma unroll
      for (int kt = 0; kt < 4; ++kt) hfrag[kt] = *(const bf16x8*)A_s[p][kt * 4 + q][l16];
      f32x4 accA = (f32x4){0.f, 0.f, 0.f, 0.f};
      f32x4 accB = (f32x4){0.f, 0.f, 0.f, 0.f};
#pragma unroll
      for (int kt = 0; kt < 4; ++kt)
        accA = __builtin_amdgcn_mfma_f32_16x16x32_bf16(wfA[kt], hfrag[kt], accA, 0, 0, 0);
      if (bvalid) {
#pragma unroll
        for (int kt = 0; kt < 4; ++kt)
          accB = __builtin_amdgcn_mfma_f32_16x16x32_bf16(wfB[kt], hfrag[kt], accB, 0, 0, 0);
      }
      float pb0 = partner8(accB[0]), pb1 = partner8(accB[1]);
      float pb2 = partner8(accB[2]), pb3 = partner8(accB[3]);
      float g0 = up ? pb0 : accA[0];
      float g1 = up ? pb1 : accA[1];
      float g2 = up ? pb2 : accA[2];
      float g3 = up ? pb3 : accA[3];
      float cc = sigm(g1) * c + sigm(g0) * tanhf_(g2);
      c = cc;
      float h = sigm(g3) * tanhf_(cc);
      if (valid) A_s[1 - p][j >> 3][mm][j & 7] = (short)f2bf(h);
      if (do_x) {
        int k = 100 + xe;
        A_s[1 - p][k >> 3][xm][k & 7] = (short)f2bf(xn);
      }
      barrier_nv();
      p ^= 1;
    }
    if (tid < 200) *(uint2*)hp = *(const uint2*)&A_s[p][sj >> 3][sm][sj & 7];
  }
  __threadfence();
  grid.sync();

  // ================= P2: gemm_xg (8 row-groups of 64 per block) =================
  {
    auto B_s = (short(*)[64][8])smem;  // [28][64][8]
    const int mtA = w, mtB = w + 16;
    const bool bvalid = (mtB < NT);
    bf16x8 wfA[7], wfB[7];
#pragma unroll
    for (int kt = 0; kt < 7; ++kt) {
      wfA[kt] = *(const bf16x8*)(pkxg + ((size_t)(kt * 4 + q) * NP + mtA * 16 + l16) * 8);
      wfB[kt] = *(const bf16x8*)(pkxg + ((size_t)(kt * 4 + q) * NP + mtB * 16 + l16) * 8);
    }
    const int jA = mtA * 4 + q, jB = mtB * 4 + q;
    // bias-one rows (kg 25..27) are g-invariant: stage once
    __syncthreads();
    for (int i = tid; i < 3 * 64 * 8; i += 1024) {
      int jj = i & 7, gl = i >> 9;
      ((short*)&B_s[25][0][0])[i] = (short)((gl == 0 && jj == 0) ? f2bf(1.f) : 0);
    }
    for (int g = 0; g < 8; ++g) {
      const int r0 = (bid * 8 + g) * 64;
      const size_t base = (size_t)r0 * H;
      __syncthreads();  // previous iteration's reads complete
      for (int idx = tid; idx < 1600; idx += 1024) {
        int m = idx / 25, j0 = (idx - (idx / 25) * 25) * 4;
        *(uint2*)&B_s[j0 >> 3][m][j0 & 7] = *(const uint2*)(h0fT + base + m * H + j0);
        int k = 100 + j0;
        *(uint2*)&B_s[k >> 3][m][k & 7] = *(const uint2*)(h0bT + base + m * H + j0);
      }
      __syncthreads();
#pragma unroll
      for (int rg = 0; rg < 4; ++rg) {
        f32x4 accA = (f32x4){0.f, 0.f, 0.f, 0.f};
        f32x4 accB = (f32x4){0.f, 0.f, 0.f, 0.f};
#pragma unroll
        for (int kt = 0; kt < 7; ++kt) {
          bf16x8 hf = *(const bf16x8*)B_s[kt * 4 + q][rg * 16 + l16];
          accA = __builtin_amdgcn_mfma_f32_16x16x32_bf16(wfA[kt], hf, accA, 0, 0, 0);
          if (bvalid)
            accB = __builtin_amdgcn_mfma_f32_16x16x32_bf16(wfB[kt], hf, accB, 0, 0, 0);
        }
        const size_t row = (size_t)(r0 + rg * 16 + l16);
        {
          __half2 h01 = __floats2half2_rn(accA[0], accA[1]);
          __half2 h23 = __floats2half2_rn(accA[2], accA[3]);
          uint2 st; *(__half2*)&st.x = h01; *(__half2*)&st.y = h23;
          *(uint2*)(xg + row * G + 4 * jA) = st;
        }
        if (bvalid) {
          __half2 h01 = __floats2half2_rn(accB[0], accB[1]);
          __half2 h23 = __floats2half2_rn(accB[2], accB[3]);
          uint2 st; *(__half2*)&st.x = h01; *(__half2*)&st.y = h23;
          *(uint2*)(xg + row * G + 4 * jB) = st;
        }
      }
    }
  }
  __threadfence();
  grid.sync();

  // ================= P3: layer-1 scan + epilogue (blocks 0..127) =================
  if (bid < 128) {
    auto A_s  = (short(*)[16][16][8])smem;            // [2][16][16][8], 8192 B
    auto A2_s = (short(*)[16][8])(smem + 8192);       // [28][16][8], 7168 B
    float* hf_s   = (float*)(smem + 15360);           // [8][100]
    float* hb_s   = (float*)(smem + 18560);           // [8][100]
    float* fcw_s  = (float*)(smem + 21760);           // [600]
    float* fcb_s  = (float*)(smem + 24160);           // [3]
    float* logit_s = (float*)(smem + 24176);          // [8][3]

    const int b0 = bid * MB;
    const uint2* xg2 = (const uint2*)xg;

    for (int i = tid; i < 2 * 16 * 16 * 8; i += 1024) ((short*)A_s)[i] = 0;
    for (int i = tid; i < 25 * 16 * 8; i += 1024) ((short*)A2_s)[i] = 0;
    for (int i = tid; i < 3 * 16 * 8; i += 1024) {
      int jj = i & 7, gl = i >> 7;
      ((short*)&A2_s[25][0][0])[i] = (short)((gl == 0 && jj == 0) ? f2bf(1.f) : 0);
    }
    for (int i = tid; i < 3 * D1; i += 1024) fcw_s[i] = fc_w[i];
    if (tid < 3) fcb_s[tid] = fc_b[tid];

    const int mtA = w, mtB = w + 16;
    const bool bvalid = (mtB < NT);
    bf16x8 wfA[4], wfB[4];
#pragma unroll
    for (int kt = 0; kt < 4; ++kt) {
      wfA[kt] = *(const bf16x8*)(pkhh + ((size_t)(kt * 4 + q) * NP + mtA * 16 + l16) * 8);
      wfB[kt] = *(const bf16x8*)(pkhh + ((size_t)(kt * 4 + q) * NP + mtB * 16 + l16) * 8);
    }
    float c = 0.f;
    const bool up = (l16 >= 8);
    const int mm = l16 & 7;
    const int j = (up ? mtB : mtA) * 4 + q;
    const bool valid = up ? bvalid : true;
    const int jA = mtA * 4 + q;
    const int jB = mtB * 4 + q;
    const uint2* xgpA = xg2 + (size_t)(b0 + mm) * 100 + jA;
    const uint2* xgpB = xg2 + (size_t)(b0 + mm) * 100 + jB;
    uint2 xgCurA = xgpA[0], xgCurB = xgpB[0];  // t=0
    xgpA += Bsz * 100; xgpB += Bsz * 100;
    float h_last = 0.f;
    __syncthreads();

    int p = 0;
    for (int t = 0; t < Tt; ++t) {
      uint2 xgNxtA = xgCurA, xgNxtB = xgCurB;
      if (t < Tt - 1) {
        xgNxtA = *xgpA; xgNxtB = *xgpB;
        xgpA += Bsz * 100; xgpB += Bsz * 100;
      }
      float2 a01 = __half22float2(*(const __half2*)&xgCurA.x);
      float2 a23 = __half22float2(*(const __half2*)&xgCurA.y);
      float2 b01 = __half22float2(*(const __half2*)&xgCurB.x);
      float2 b23 = __half22float2(*(const __half2*)&xgCurB.y);
      f32x4 accA = (f32x4){a01.x, a01.y, a23.x, a23.y};
      f32x4 accB = (f32x4){b01.x, b01.y, b23.x, b23.y};
      bf16x8 hfrag[4];
#pragma unroll
      for (int kt = 0; kt < 4; ++kt) hfrag[kt] = *(const bf16x8*)A_s[p][kt * 4 + q][l16];
#pragma unroll
      for (int kt = 0; kt < 4; ++kt)
        accA = __builtin_amdgcn_mfma_f32_16x16x32_bf16(wfA[kt], hfrag[kt], accA, 0, 0, 0);
      if (bvalid) {
#pragma unroll
        for (int kt = 0; kt < 4; ++kt)
          accB = __builtin_amdgcn_mfma_f32_16x16x32_bf16(wfB[kt], hfrag[kt], accB, 0, 0, 0);
      }
      float pb0 = partner8(accB[0]), pb1 = partner8(accB[1]);
      float pb2 = partner8(accB[2]), pb3 = partner8(accB[3]);
      float g0 = up ? pb0 : accA[0];
      float g1 = up ? pb1 : accA[1];
      float g2 = up ? pb2 : accA[2];
      float g3 = up ? pb3 : accA[3];
      float cc = sigm(g1) * c + sigm(g0) * tanhf_(g2);
      c = cc;
      float h = sigm(g3) * tanhf_(cc);
      if (valid) A_s[1 - p][j >> 3][mm][j & 7] = (short)f2bf(h);
      h_last = h;
      xgCurA = xgNxtA; xgCurB = xgNxtB;
      barrier_nv();
      p ^= 1;
    }
    if (valid) hf_s[mm * H + j] = h_last;

    // layer-1 backward single step at t=T-1 (h=c=0)
    {
      const size_t base = ((size_t)(Tt - 1) * Bsz + b0) * H;
      if (tid < 200) {
        int m = tid / 25, j0 = (tid - (tid / 25) * 25) * 4;
        *(uint2*)&A2_s[j0 >> 3][m][j0 & 7] = *(const uint2*)(h0fT + base + m * H + j0);
        int k = 100 + j0;
        *(uint2*)&A2_s[k >> 3][m][k & 7] = *(const uint2*)(h0bT + base + m * H + j0);
      }
    }
    __syncthreads();
    {
      f32x4 accA = (f32x4){0.f, 0.f, 0.f, 0.f};
      f32x4 accB = (f32x4){0.f, 0.f, 0.f, 0.f};
#pragma unroll
      for (int kt = 0; kt < 7; ++kt) {
        bf16x8 hf = *(const bf16x8*)A2_s[kt * 4 + q][l16];
        bf16x8 wfa = *(const bf16x8*)(pk1b + ((size_t)(kt * 4 + q) * NP + mtA * 16 + l16) * 8);
        accA = __builtin_amdgcn_mfma_f32_16x16x32_bf16(wfa, hf, accA, 0, 0, 0);
        if (bvalid) {
          bf16x8 wfb = *(const bf16x8*)(pk1b + ((size_t)(kt * 4 + q) * NP + mtB * 16 + l16) * 8);
          accB = __builtin_amdgcn_mfma_f32_16x16x32_bf16(wfb, hf, accB, 0, 0, 0);
        }
      }
      float pb0 = partner8(accB[0]);
      float pb2 = partner8(accB[2]);
      float pb3 = partner8(accB[3]);
      float g0 = up ? pb0 : accA[0];
      float g2 = up ? pb2 : accA[2];
      float g3 = up ? pb3 : accA[3];
      float cc = sigm(g0) * tanhf_(g2);   // c_prev = 0
      if (valid) hb_s[mm * H + j] = sigm(g3) * tanhf_(cc);
    }
    __syncthreads();

    // FC (3x200) + softmax
    if (tid < MB * 3) {
      int m = tid / 3, cls = tid - m * 3;
      float s = fcb_s[cls];
      for (int jj = 0; jj < H; ++jj) s += fcw_s[cls * D1 + jj] * hf_s[m * H + jj];
      for (int jj = 0; jj < H; ++jj) s += fcw_s[cls * D1 + H + jj] * hb_s[m * H + jj];
      logit_s[m * 3 + cls] = s;
    }
    __syncthreads();
    if (tid < MB) {
      float a = logit_s[tid * 3 + 0], b = logit_s[tid * 3 + 1], cc = logit_s[tid * 3 + 2];
      float mx = fmaxf(a, fmaxf(b, cc));
      float e0 = __expf(a - mx), e1 = __expf(b - mx), e2 = __expf(cc - mx);
      float inv = 1.f / (e0 + e1 + e2);
      out[(b0 + tid) * 3 + 0] = e0 * inv;
      out[(b0 + tid) * 3 + 1] = e1 * inv;
      out[(b0 + tid) * 3 + 2] = e2 * inv;
    }
  }
}

extern "C" void kernel_launch(void* const* d_in, const int* in_sizes, int n_in,
                              void* d_out, int out_size, void* d_ws, size_t ws_size,
                              hipStream_t stream) {
  const float* x        = (const float*)d_in[0];
  const float* w_ih_l0f = (const float*)d_in[1];
  const float* w_hh_l0f = (const float*)d_in[2];
  const float* b_ih_l0f = (const float*)d_in[3];
  const float* b_hh_l0f = (const float*)d_in[4];
  const float* w_ih_l0b = (const float*)d_in[5];
  const float* w_hh_l0b = (const float*)d_in[6];
  const float* b_ih_l0b = (const float*)d_in[7];
  const float* b_hh_l0b = (const float*)d_in[8];
  const float* w_ih_l1f = (const float*)d_in[9];
  const float* w_hh_l1f = (const float*)d_in[10];
  const float* b_ih_l1f = (const float*)d_in[11];
  const float* b_hh_l1f = (const float*)d_in[12];
  const float* w_ih_l1b = (const float*)d_in[13];
  // d_in[14] = w_hh_l1b unused (reverse dir at t=T-1 has h=0)
  const float* b_ih_l1b = (const float*)d_in[15];
  const float* b_hh_l1b = (const float*)d_in[16];
  const float* fc_w     = (const float*)d_in[17];
  const float* fc_b     = (const float*)d_in[18];

  unsigned short* h0fT = (unsigned short*)d_ws;
  unsigned short* h0bT = h0fT + (size_t)Tt * Bsz * H;
  __half* xgT          = (__half*)(h0bT + (size_t)Tt * Bsz * H);
  unsigned short* pk0f = (unsigned short*)(xgT + (size_t)Tt * Bsz * G);
  unsigned short* pk0b = pk0f + 16 * NP * 8;
  unsigned short* pkhh = pk0b + 16 * NP * 8;
  unsigned short* pkxg = pkhh + 16 * NP * 8;
  unsigned short* pk1b = pkxg + 28 * NP * 8;
  float* outp = (float*)d_out;

  void* kargs[] = {
    (void*)&x,
    (void*)&w_ih_l0f, (void*)&w_hh_l0f, (void*)&b_ih_l0f, (void*)&b_hh_l0f,
    (void*)&w_ih_l0b, (void*)&w_hh_l0b, (void*)&b_ih_l0b, (void*)&b_hh_l0b,
    (void*)&w_ih_l1f, (void*)&w_hh_l1f, (void*)&b_ih_l1f, (void*)&b_hh_l1f,
    (void*)&w_ih_l1b, (void*)&b_ih_l1b, (void*)&b_hh_l1b,
    (void*)&fc_w, (void*)&fc_b,
    (void*)&pk0f, (void*)&pk0b, (void*)&pkhh, (void*)&pkxg, (void*)&pk1b,
    (void*)&h0fT, (void*)&h0bT, (void*)&xgT, (void*)&outp,
  };
  hipLaunchCooperativeKernel((void*)lstm_mega, dim3(256), dim3(1024),
                             kargs, 0, stream);
}

// Round 13
// 390.606 us; speedup vs baseline: 1.8546x; 1.8546x over previous
//
#include <hip/hip_runtime.h>
#include <hip/hip_fp16.h>

// LSTM_48850958024796 — R13: best-of reassembly.
//  - 4 kernels (boundaries provide cross-XCD coherence cheaply; R12's fused
//    cooperative kernel forced 157MB of intermediates through HBM: 724 µs)
//  - scans: R10-exact loop form (__syncthreads, no unroll — barrier_nv and
//    unroll-2 both measured slightly negative in R11), 8-row spread via
//    exec-safe ds_swizzle(0x17), register-resident weights, register-direct
//    xg prefetch with running pointers
//  - gemm_xg: R11 weight-stationary (1 barrier, reg-resident weights): -44 µs
// Scan math (R3-proven): gates^T = W(A) @ [h|x|1]^T(B), cols gate-interleaved
// (n'=4j+gate): lane(q,l16) of tile mt holds gates i,f,g,o of (m=l16&7,
// j=mt*4+q) in acc[0..3]; lanes l16>=8 take tile B's gates from lane&~8.

typedef __attribute__((ext_vector_type(8))) short bf16x8;
typedef __attribute__((ext_vector_type(4))) float f32x4;

constexpr int Bsz = 1024, Tt = 128, IN_ = 5, H = 100, G = 400, D1 = 200;
constexpr int NP = 512;   // packed gate cols (32 tiles of 16)
constexpr int NT = 25;    // real tiles (400/16)
constexpr int MB = 8;     // batch rows per block (scans)

__device__ __forceinline__ float sigm(float x)   { return 1.f / (1.f + __expf(-x)); }
__device__ __forceinline__ float tanhf_(float x) { return 1.f - 2.f / (__expf(2.f * x) + 1.f); }
__device__ __forceinline__ unsigned short f2bf(float f) {
  unsigned u = __float_as_uint(f);
  u += 0x7fff + ((u >> 16) & 1);
  return (unsigned short)(u >> 16);
}
// every lane receives the value held by lane (lane & ~8); unconditional.
__device__ __forceinline__ float partner8(float v) {
  return __uint_as_float(
      (unsigned)__builtin_amdgcn_ds_swizzle((int)__float_as_uint(v), 0x17));
}

// packed col n' (0..511): j=n'>>2, gate=n'&3, src row n = gate*100+j; j>=100->0
__device__ __forceinline__ void pack_body(
    const float* wA, int KA, const float* wB, int KB, int kbo,
    const float* b1, const float* b2, int bias_k,
    unsigned short* dst, int Kg, int idx) {
  if (idx >= Kg * NP * 8) return;
  int jj = idx & 7, rest = idx >> 3;
  int np_ = rest % NP, g = rest / NP;
  int j = np_ >> 2, gate = np_ & 3;
  int k = g * 8 + jj;
  float v = 0.f;
  if (j < H) {
    int n = gate * H + j;
    if (k < KA) v = wA[n * KA + k];
    else if (KB > 0 && k >= kbo && k < kbo + KB) v = wB[n * KB + (k - kbo)];
    else if (k == bias_k) v = b1[n] + b2[n];
  }
  dst[idx] = f2bf(v);
}

__global__ void pack_all(
    const float* __restrict__ w_hh_l0f, const float* __restrict__ w_ih_l0f,
    const float* __restrict__ b_ih_l0f, const float* __restrict__ b_hh_l0f,
    const float* __restrict__ w_hh_l0b, const float* __restrict__ w_ih_l0b,
    const float* __restrict__ b_ih_l0b, const float* __restrict__ b_hh_l0b,
    const float* __restrict__ w_hh_l1f, const float* __restrict__ b_ih_l1f,
    const float* __restrict__ b_hh_l1f,
    const float* __restrict__ w_ih_l1f, const float* __restrict__ w_ih_l1b,
    const float* __restrict__ b_ih_l1b, const float* __restrict__ b_hh_l1b,
    unsigned short* __restrict__ pk0f, unsigned short* __restrict__ pk0b,
    unsigned short* __restrict__ pkhh, unsigned short* __restrict__ pkxg,
    unsigned short* __restrict__ pk1b) {
  int idx = blockIdx.x * 256 + threadIdx.x;
  switch (blockIdx.y) {
    case 0: pack_body(w_hh_l0f, 100, w_ih_l0f, 5, 100, b_ih_l0f, b_hh_l0f, 105, pk0f, 16, idx); break;
    case 1: pack_body(w_hh_l0b, 100, w_ih_l0b, 5, 100, b_ih_l0b, b_hh_l0b, 105, pk0b, 16, idx); break;
    case 2: pack_body(w_hh_l1f, 100, nullptr, 0, 0, b_ih_l1f, b_hh_l1f, -1, pkhh, 16, idx); break;
    case 3: pack_body(w_ih_l1f, 200, nullptr, 0, 0, b_ih_l1f, b_hh_l1f, 200, pkxg, 28, idx); break;
    default: pack_body(w_ih_l1b, 200, nullptr, 0, 0, b_ih_l1b, b_hh_l1b, 200, pk1b, 28, idx);
  }
}

// ------------- layer 0 scan (grid = 128 x 2 dirs, 1024 thr) -----------------
__global__ __launch_bounds__(1024, 1) void lstm_l0(
    const float* __restrict__ x,
    const unsigned short* __restrict__ pk_f, const unsigned short* __restrict__ pk_b,
    unsigned short* __restrict__ h0fT, unsigned short* __restrict__ h0bT) {
  __shared__ __align__(16) short A_s[2][16][16][8];  // [buf][kg][m16][jj], K=128

  const int tid = threadIdx.x;
  const int lane = tid & 63, w = tid >> 6;       // 16 waves
  const int q = lane >> 4, l16 = lane & 15;
  const int b0 = blockIdx.x * MB;
  const int dir = blockIdx.y;
  const unsigned short* pk = dir ? pk_b : pk_f;
  unsigned short* hT = dir ? h0bT : h0fT;

  for (int i = tid; i < 2 * 16 * 16 * 8; i += 1024) ((short*)A_s)[i] = 0;

  const int mtA = w, mtB = w + 16;
  const bool bvalid = (mtB < NT);
  bf16x8 wfA[4], wfB[4];
#pragma unroll
  for (int kt = 0; kt < 4; ++kt) {
    wfA[kt] = *(const bf16x8*)(pk + ((size_t)(kt * 4 + q) * NP + mtA * 16 + l16) * 8);
    wfB[kt] = *(const bf16x8*)(pk + ((size_t)(kt * 4 + q) * NP + mtB * 16 + l16) * 8);
  }
  float c = 0.f;
  const bool up = (l16 >= 8);
  const int mm = l16 & 7;
  const int j = (up ? mtB : mtA) * 4 + q;
  const bool valid = up ? bvalid : true;
  const int xm = tid / IN_, xe = tid - xm * IN_;              // x loader (tid<40)
  const int sm = tid / 25, sj = (tid - (tid / 25) * 25) * 4;  // h store (tid<200)
  // running pointers (stride add per step, no per-step 64-bit recompute)
  const float* xp = x + ((size_t)(b0 + xm) * Tt + (dir ? Tt - 2 : 1)) * IN_ + xe;
  const int xstride = dir ? -IN_ : IN_;
  unsigned short* hp =
      hT + ((size_t)(dir ? Tt - 1 : 0) * Bsz + b0 + sm) * H + sj;
  const int hstride = dir ? -(Bsz * H) : (Bsz * H);
  __syncthreads();
  if (tid < 16) {  // bias-one col k=105 (kg13,jj1), both bufs
    A_s[0][13][tid][1] = (short)f2bf(1.f);
    A_s[1][13][tid][1] = (short)f2bf(1.f);
  }
  if (tid < MB * IN_) {  // x(t_first) -> buf0, direct f32 read
    int t0 = dir ? (Tt - 1) : 0;
    int k = 100 + xe;
    A_s[0][k >> 3][xm][k & 7] =
        (short)f2bf(x[((size_t)(b0 + xm) * Tt + t0) * IN_ + xe]);
  }
  __syncthreads();

  int p = 0;
  for (int step = 0; step < Tt; ++step) {
    if (step > 0 && tid < 200) {  // coalesced store of h(prev) from buf p
      uint2 hv = *(const uint2*)&A_s[p][sj >> 3][sm][sj & 7];
      *(uint2*)hp = hv;
      hp += hstride;
    }
    float xn = 0.f;
    const bool do_x = (tid < MB * IN_) && (step < Tt - 1);
    if (do_x) { xn = *xp; xp += xstride; }
    bf16x8 hfrag[4];
#pragma unroll
    for (int kt = 0; kt < 4; ++kt) hfrag[kt] = *(const bf16x8*)A_s[p][kt * 4 + q][l16];
    f32x4 accA = (f32x4){0.f, 0.f, 0.f, 0.f};
    f32x4 accB = (f32x4){0.f, 0.f, 0.f, 0.f};
#pragma unroll
    for (int kt = 0; kt < 4; ++kt)
      accA = __builtin_amdgcn_mfma_f32_16x16x32_bf16(wfA[kt], hfrag[kt], accA, 0, 0, 0);
    if (bvalid) {
#pragma unroll
      for (int kt = 0; kt < 4; ++kt)
        accB = __builtin_amdgcn_mfma_f32_16x16x32_bf16(wfB[kt], hfrag[kt], accB, 0, 0, 0);
    }
    // exec-safe spread: every lane swizzles unconditionally, then selects
    float pb0 = partner8(accB[0]), pb1 = partner8(accB[1]);
    float pb2 = partner8(accB[2]), pb3 = partner8(accB[3]);
    float g0 = up ? pb0 : accA[0];
    float g1 = up ? pb1 : accA[1];
    float g2 = up ? pb2 : accA[2];
    float g3 = up ? pb3 : accA[3];
    float cc = sigm(g1) * c + sigm(g0) * tanhf_(g2);
    c = cc;
    float h = sigm(g3) * tanhf_(cc);
    if (valid) A_s[1 - p][j >> 3][mm][j & 7] = (short)f2bf(h);
    if (do_x) {
      int k = 100 + xe;
      A_s[1 - p][k >> 3][xm][k & 7] = (short)f2bf(xn);
    }
    __syncthreads();
    p ^= 1;
  }
  if (tid < 200) *(uint2*)hp = *(const uint2*)&A_s[p][sj >> 3][sm][sj & 7];  // final h
}

// ---- xgT[t*1024+b][400] = [h0f|h0b] @ W_ih_l1f^T + bias (fp16, interleaved) --
// Weight-stationary: weights as A-operand in regs (2 tiles x 7 kt per wave),
// 64 rows staged once in LDS as B, ONE barrier, 4 row-groups.
__global__ __launch_bounds__(1024, 1) void gemm_xg(
    const unsigned short* __restrict__ h0fT, const unsigned short* __restrict__ h0bT,
    const unsigned short* __restrict__ pkw, __half* __restrict__ xg) {
  __shared__ __align__(16) short B_s[28][64][8];  // K=224 aug (k=200 bias-one)
  const int tid = threadIdx.x;
  const int lane = tid & 63, w = tid >> 6;   // 16 waves
  const int q = lane >> 4, l16 = lane & 15;
  const int r0 = blockIdx.x * 64;            // rows r = t*1024+b
  const size_t base = (size_t)r0 * H;

  for (int i = tid; i < 3 * 64 * 8; i += 1024) {  // kg 25..27: zero + bias-one
    int jj = i & 7, gl = i >> 9;
    ((short*)&B_s[25][0][0])[i] = (short)((gl == 0 && jj == 0) ? f2bf(1.f) : 0);
  }
  for (int idx = tid; idx < 1600; idx += 1024) {  // h0f k=0..99, h0b k=100..199
    int m = idx / 25, j0 = (idx - (idx / 25) * 25) * 4;
    *(uint2*)&B_s[j0 >> 3][m][j0 & 7] = *(const uint2*)(h0fT + base + m * H + j0);
    int k = 100 + j0;
    *(uint2*)&B_s[k >> 3][m][k & 7] = *(const uint2*)(h0bT + base + m * H + j0);
  }

  const int mtA = w, mtB = w + 16;
  const bool bvalid = (mtB < NT);
  bf16x8 wfA[7], wfB[7];
#pragma unroll
  for (int kt = 0; kt < 7; ++kt) {
    wfA[kt] = *(const bf16x8*)(pkw + ((size_t)(kt * 4 + q) * NP + mtA * 16 + l16) * 8);
    wfB[kt] = *(const bf16x8*)(pkw + ((size_t)(kt * 4 + q) * NP + mtB * 16 + l16) * 8);
  }
  const int jA = mtA * 4 + q, jB = mtB * 4 + q;
  __syncthreads();

#pragma unroll
  for (int rg = 0; rg < 4; ++rg) {
    f32x4 accA = (f32x4){0.f, 0.f, 0.f, 0.f};
    f32x4 accB = (f32x4){0.f, 0.f, 0.f, 0.f};
#pragma unroll
    for (int kt = 0; kt < 7; ++kt) {
      bf16x8 hf = *(const bf16x8*)B_s[kt * 4 + q][rg * 16 + l16];
      accA = __builtin_amdgcn_mfma_f32_16x16x32_bf16(wfA[kt], hf, accA, 0, 0, 0);
      if (bvalid)
        accB = __builtin_amdgcn_mfma_f32_16x16x32_bf16(wfB[kt], hf, accB, 0, 0, 0);
    }
    const size_t row = (size_t)(r0 + rg * 16 + l16);
    {
      __half2 h01 = __floats2half2_rn(accA[0], accA[1]);
      __half2 h23 = __floats2half2_rn(accA[2], accA[3]);
      uint2 st; *(__half2*)&st.x = h01; *(__half2*)&st.y = h23;
      *(uint2*)(xg + row * G + 4 * jA) = st;
    }
    if (bvalid) {
      __half2 h01 = __floats2half2_rn(accB[0], accB[1]);
      __half2 h23 = __floats2half2_rn(accB[2], accB[3]);
      uint2 st; *(__half2*)&st.x = h01; *(__half2*)&st.y = h23;
      *(uint2*)(xg + row * G + 4 * jB) = st;
    }
  }
}

// ---- layer 1: fwd scan + bwd single step + FC + softmax (128 blk, 1024 thr) --
__global__ __launch_bounds__(1024, 1) void lstm_l1(
    const unsigned short* __restrict__ h0fT, const unsigned short* __restrict__ h0bT,
    const unsigned short* __restrict__ pk_hh, const unsigned short* __restrict__ pk1b,
    const __half* __restrict__ xg,
    const float* __restrict__ fc_w, const float* __restrict__ fc_b,
    float* __restrict__ out) {
  __shared__ __align__(16) short A_s[2][16][16][8];      // h1, K=128
  __shared__ __align__(16) short A2_s[28][16][8];        // epilogue [h0|1] K=224
  __shared__ float hf_s[MB][H];
  __shared__ float hb_s[MB][H];
  __shared__ float fcw_s[3 * D1];
  __shared__ float fcb_s[3];
  __shared__ float logit_s[MB][3];

  const int tid = threadIdx.x;
  const int lane = tid & 63, w = tid >> 6;   // 16 waves
  const int q = lane >> 4, l16 = lane & 15;
  const int b0 = blockIdx.x * MB;
  const uint2* xg2 = (const uint2*)xg;       // 100 uint2 per (t,b) row

  for (int i = tid; i < 2 * 16 * 16 * 8; i += 1024) ((short*)A_s)[i] = 0;
  for (int i = tid; i < 25 * 16 * 8; i += 1024) ((short*)A2_s)[i] = 0;  // kg 0..24
  for (int i = tid; i < 3 * 16 * 8; i += 1024) {  // A2 kg25..27 zero + bias-one
    int jj = i & 7, gl = i >> 7;
    ((short*)&A2_s[25][0][0])[i] = (short)((gl == 0 && jj == 0) ? f2bf(1.f) : 0);
  }
  for (int i = tid; i < 3 * D1; i += 1024) fcw_s[i] = fc_w[i];
  if (tid < 3) fcb_s[tid] = fc_b[tid];

  const int mtA = w, mtB = w + 16;
  const bool bvalid = (mtB < NT);
  bf16x8 wfA[4], wfB[4];
#pragma unroll
  for (int kt = 0; kt < 4; ++kt) {
    wfA[kt] = *(const bf16x8*)(pk_hh + ((size_t)(kt * 4 + q) * NP + mtA * 16 + l16) * 8);
    wfB[kt] = *(const bf16x8*)(pk_hh + ((size_t)(kt * 4 + q) * NP + mtB * 16 + l16) * 8);
  }
  float c = 0.f;
  const bool up = (l16 >= 8);
  const int mm = l16 & 7;
  const int j = (up ? mtB : mtA) * 4 + q;
  const bool valid = up ? bvalid : true;
  // register-direct xg prefetch with running pointers (+102400 uint2 per t);
  // invalid-lane jB reads land <=224B past xg (adjacent ws region), unused.
  const int jA = mtA * 4 + q;
  const int jB = mtB * 4 + q;
  const uint2* xgpA = xg2 + (size_t)(b0 + mm) * 100 + jA;
  const uint2* xgpB = xg2 + (size_t)(b0 + mm) * 100 + jB;
  uint2 xgCurA = xgpA[0], xgCurB = xgpB[0];  // t=0
  xgpA += Bsz * 100; xgpB += Bsz * 100;
  __syncthreads();

  int p = 0;
  for (int t = 0; t < Tt; ++t) {
    uint2 xgNxtA = xgCurA, xgNxtB = xgCurB;
    if (t < Tt - 1) {
      xgNxtA = *xgpA; xgNxtB = *xgpB;
      xgpA += Bsz * 100; xgpB += Bsz * 100;
    }
    // acc init from xg (gates i,f,g,o of (m=mm, j))
    float2 a01 = __half22float2(*(const __half2*)&xgCurA.x);
    float2 a23 = __half22float2(*(const __half2*)&xgCurA.y);
    float2 b01 = __half22float2(*(const __half2*)&xgCurB.x);
    float2 b23 = __half22float2(*(const __half2*)&xgCurB.y);
    f32x4 accA = (f32x4){a01.x, a01.y, a23.x, a23.y};
    f32x4 accB = (f32x4){b01.x, b01.y, b23.x, b23.y};
    bf16x8 hfrag[4];
#pragma unroll
    for (int kt = 0; kt < 4; ++kt) hfrag[kt] = *(const bf16x8*)A_s[p][kt * 4 + q][l16];
#pragma unroll
    for (int kt = 0; kt < 4; ++kt)
      accA = __builtin_amdgcn_mfma_f32_16x16x32_bf16(wfA[kt], hfrag[kt], accA, 0, 0, 0);
    if (bvalid) {
#pragma unroll
      for (int kt = 0; kt < 4; ++kt)
        accB = __builtin_amdgcn_mfma_f32_16x16x32_bf16(wfB[kt], hfrag[kt], accB, 0, 0, 0);
    }
    float pb0 = partner8(accB[0]), pb1 = partner8(accB[1]);
    float pb2 = partner8(accB[2]), pb3 = partner8(accB[3]);
    float g0 = up ? pb0 : accA[0];
    float g1 = up ? pb1 : accA[1];
    float g2 = up ? pb2 : accA[2];
    float g3 = up ? pb3 : accA[3];
    float cc = sigm(g1) * c + sigm(g0) * tanhf_(g2);
    c = cc;
    float h = sigm(g3) * tanhf_(cc);
    if (valid) {
      A_s[1 - p][j >> 3][mm][j & 7] = (short)f2bf(h);
      if (t == Tt - 1) hf_s[mm][j] = h;
    }
    xgCurA = xgNxtA; xgCurB = xgNxtB;
    __syncthreads();
    p ^= 1;
  }

  // ---- layer-1 backward single step at t=T-1 (h=c=0) ----
  {
    const size_t base = ((size_t)(Tt - 1) * Bsz + b0) * H;
    if (tid < 200) {
      int m = tid / 25, j0 = (tid - (tid / 25) * 25) * 4;
      *(uint2*)&A2_s[j0 >> 3][m][j0 & 7] = *(const uint2*)(h0fT + base + m * H + j0);
      int k = 100 + j0;
      *(uint2*)&A2_s[k >> 3][m][k & 7] = *(const uint2*)(h0bT + base + m * H + j0);
    }
  }
  __syncthreads();
  {
    f32x4 accA = (f32x4){0.f, 0.f, 0.f, 0.f};
    f32x4 accB = (f32x4){0.f, 0.f, 0.f, 0.f};
#pragma unroll
    for (int kt = 0; kt < 7; ++kt) {
      bf16x8 hf = *(const bf16x8*)A2_s[kt * 4 + q][l16];
      bf16x8 wfa = *(const bf16x8*)(pk1b + ((size_t)(kt * 4 + q) * NP + mtA * 16 + l16) * 8);
      accA = __builtin_amdgcn_mfma_f32_16x16x32_bf16(wfa, hf, accA, 0, 0, 0);
      if (bvalid) {
        bf16x8 wfb = *(const bf16x8*)(pk1b + ((size_t)(kt * 4 + q) * NP + mtB * 16 + l16) * 8);
        accB = __builtin_amdgcn_mfma_f32_16x16x32_bf16(wfb, hf, accB, 0, 0, 0);
      }
    }
    float pb0 = partner8(accB[0]);
    float pb2 = partner8(accB[2]);
    float pb3 = partner8(accB[3]);
    float g0 = up ? pb0 : accA[0];
    float g2 = up ? pb2 : accA[2];
    float g3 = up ? pb3 : accA[3];
    float cc = sigm(g0) * tanhf_(g2);   // c_prev = 0
    if (valid) hb_s[mm][j] = sigm(g3) * tanhf_(cc);
  }
  __syncthreads();

  // ---- FC (3x200) + softmax ----
  if (tid < MB * 3) {
    int m = tid / 3, cls = tid - m * 3;
    float s = fcb_s[cls];
    for (int jj = 0; jj < H; ++jj) s += fcw_s[cls * D1 + jj] * hf_s[m][jj];
    for (int jj = 0; jj < H; ++jj) s += fcw_s[cls * D1 + H + jj] * hb_s[m][jj];
    logit_s[m][cls] = s;
  }
  __syncthreads();
  if (tid < MB) {
    float a = logit_s[tid][0], b = logit_s[tid][1], cc = logit_s[tid][2];
    float mx = fmaxf(a, fmaxf(b, cc));
    float e0 = __expf(a - mx), e1 = __expf(b - mx), e2 = __expf(cc - mx);
    float inv = 1.f / (e0 + e1 + e2);
    out[(b0 + tid) * 3 + 0] = e0 * inv;
    out[(b0 + tid) * 3 + 1] = e1 * inv;
    out[(b0 + tid) * 3 + 2] = e2 * inv;
  }
}

extern "C" void kernel_launch(void* const* d_in, const int* in_sizes, int n_in,
                              void* d_out, int out_size, void* d_ws, size_t ws_size,
                              hipStream_t stream) {
  const float* x        = (const float*)d_in[0];
  const float* w_ih_l0f = (const float*)d_in[1];
  const float* w_hh_l0f = (const float*)d_in[2];
  const float* b_ih_l0f = (const float*)d_in[3];
  const float* b_hh_l0f = (const float*)d_in[4];
  const float* w_ih_l0b = (const float*)d_in[5];
  const float* w_hh_l0b = (const float*)d_in[6];
  const float* b_ih_l0b = (const float*)d_in[7];
  const float* b_hh_l0b = (const float*)d_in[8];
  const float* w_ih_l1f = (const float*)d_in[9];
  const float* w_hh_l1f = (const float*)d_in[10];
  const float* b_ih_l1f = (const float*)d_in[11];
  const float* b_hh_l1f = (const float*)d_in[12];
  const float* w_ih_l1b = (const float*)d_in[13];
  // d_in[14] = w_hh_l1b unused (reverse dir at t=T-1 has h=0)
  const float* b_ih_l1b = (const float*)d_in[15];
  const float* b_hh_l1b = (const float*)d_in[16];
  const float* fc_w     = (const float*)d_in[17];
  const float* fc_b     = (const float*)d_in[18];

  unsigned short* h0fT = (unsigned short*)d_ws;
  unsigned short* h0bT = h0fT + (size_t)Tt * Bsz * H;
  __half* xgT          = (__half*)(h0bT + (size_t)Tt * Bsz * H);
  unsigned short* pk0f = (unsigned short*)(xgT + (size_t)Tt * Bsz * G);
  unsigned short* pk0b = pk0f + 16 * NP * 8;
  unsigned short* pkhh = pk0b + 16 * NP * 8;
  unsigned short* pkxg = pkhh + 16 * NP * 8;
  unsigned short* pk1b = pkxg + 28 * NP * 8;

  pack_all<<<dim3(448, 5), 256, 0, stream>>>(
      w_hh_l0f, w_ih_l0f, b_ih_l0f, b_hh_l0f,
      w_hh_l0b, w_ih_l0b, b_ih_l0b, b_hh_l0b,
      w_hh_l1f, b_ih_l1f, b_hh_l1f,
      w_ih_l1f, w_ih_l1b, b_ih_l1b, b_hh_l1b,
      pk0f, pk0b, pkhh, pkxg, pk1b);

  lstm_l0<<<dim3(Bsz / MB, 2), 1024, 0, stream>>>(x, pk0f, pk0b, h0fT, h0bT);
  gemm_xg<<<(Bsz * Tt) / 64, 1024, 0, stream>>>(h0fT, h0bT, pkxg, xgT);
  lstm_l1<<<Bsz / MB, 1024, 0, stream>>>(h0fT, h0bT, pkhh, pk1b, xgT,
                                         fc_w, fc_b, (float*)d_out);
}

// Round 14
// 387.666 us; speedup vs baseline: 1.8686x; 1.0076x over previous
//
#include <hip/hip_runtime.h>
#include <hip/hip_fp16.h>

// LSTM_48850958024796 — R14: l1 goes MB=4 / 256 blocks / dense 4-tiles-per-wave.
// Waves 0..6 own tiles 4w..4w+3 (25 real tiles); each of their lanes owns ONE
// (m=l16&3, j=(4w+g16)*4+q) element; waves 7..15 are barrier-only (wave-uniform
// skip = real issue savings). Gates spread via 4x ds_swizzle(0x13) (src lane =
// same q, l16=m) + 2-level select; xg added post-spread from per-lane load.
// l0 / gemm_xg / pack unchanged from R13 (l0 at MB=4 computed net-negative:
// doubles per-CU MFMA at constant cell issue).
// Scan math (R3-proven): gates^T = W(A) @ [h|x|1]^T(B), cols gate-interleaved
// (n'=4j+gate): lane(q,l16) of tile mt holds gates i,f,g,o of col m=l16.

typedef __attribute__((ext_vector_type(8))) short bf16x8;
typedef __attribute__((ext_vector_type(4))) float f32x4;

constexpr int Bsz = 1024, Tt = 128, IN_ = 5, H = 100, G = 400, D1 = 200;
constexpr int NP = 512;   // packed gate cols (32 tiles of 16)
constexpr int NT = 25;    // real tiles (400/16)
constexpr int MB = 8;     // batch rows per block (l0)
constexpr int MB1 = 4;    // batch rows per block (l1)

__device__ __forceinline__ float sigm(float x)   { return 1.f / (1.f + __expf(-x)); }
__device__ __forceinline__ float tanhf_(float x) { return 1.f - 2.f / (__expf(2.f * x) + 1.f); }
__device__ __forceinline__ unsigned short f2bf(float f) {
  unsigned u = __float_as_uint(f);
  u += 0x7fff + ((u >> 16) & 1);
  return (unsigned short)(u >> 16);
}
// src lane = lane & ~8 (same q-bit4; keeps bits 0,1,2): MB=8 2-way spread
__device__ __forceinline__ float partner8(float v) {
  return __uint_as_float(
      (unsigned)__builtin_amdgcn_ds_swizzle((int)__float_as_uint(v), 0x17));
}
// src lane = lane & ~12 (keeps bits 0,1 and 4): MB1=4 4-way spread
__device__ __forceinline__ float partner4(float v) {
  return __uint_as_float(
      (unsigned)__builtin_amdgcn_ds_swizzle((int)__float_as_uint(v), 0x13));
}

// packed col n' (0..511): j=n'>>2, gate=n'&3, src row n = gate*100+j; j>=100->0
__device__ __forceinline__ void pack_body(
    const float* wA, int KA, const float* wB, int KB, int kbo,
    const float* b1, const float* b2, int bias_k,
    unsigned short* dst, int Kg, int idx) {
  if (idx >= Kg * NP * 8) return;
  int jj = idx & 7, rest = idx >> 3;
  int np_ = rest % NP, g = rest / NP;
  int j = np_ >> 2, gate = np_ & 3;
  int k = g * 8 + jj;
  float v = 0.f;
  if (j < H) {
    int n = gate * H + j;
    if (k < KA) v = wA[n * KA + k];
    else if (KB > 0 && k >= kbo && k < kbo + KB) v = wB[n * KB + (k - kbo)];
    else if (k == bias_k) v = b1[n] + b2[n];
  }
  dst[idx] = f2bf(v);
}

__global__ void pack_all(
    const float* __restrict__ w_hh_l0f, const float* __restrict__ w_ih_l0f,
    const float* __restrict__ b_ih_l0f, const float* __restrict__ b_hh_l0f,
    const float* __restrict__ w_hh_l0b, const float* __restrict__ w_ih_l0b,
    const float* __restrict__ b_ih_l0b, const float* __restrict__ b_hh_l0b,
    const float* __restrict__ w_hh_l1f, const float* __restrict__ b_ih_l1f,
    const float* __restrict__ b_hh_l1f,
    const float* __restrict__ w_ih_l1f, const float* __restrict__ w_ih_l1b,
    const float* __restrict__ b_ih_l1b, const float* __restrict__ b_hh_l1b,
    unsigned short* __restrict__ pk0f, unsigned short* __restrict__ pk0b,
    unsigned short* __restrict__ pkhh, unsigned short* __restrict__ pkxg,
    unsigned short* __restrict__ pk1b) {
  int idx = blockIdx.x * 256 + threadIdx.x;
  switch (blockIdx.y) {
    case 0: pack_body(w_hh_l0f, 100, w_ih_l0f, 5, 100, b_ih_l0f, b_hh_l0f, 105, pk0f, 16, idx); break;
    case 1: pack_body(w_hh_l0b, 100, w_ih_l0b, 5, 100, b_ih_l0b, b_hh_l0b, 105, pk0b, 16, idx); break;
    case 2: pack_body(w_hh_l1f, 100, nullptr, 0, 0, b_ih_l1f, b_hh_l1f, -1, pkhh, 16, idx); break;
    case 3: pack_body(w_ih_l1f, 200, nullptr, 0, 0, b_ih_l1f, b_hh_l1f, 200, pkxg, 28, idx); break;
    default: pack_body(w_ih_l1b, 200, nullptr, 0, 0, b_ih_l1b, b_hh_l1b, 200, pk1b, 28, idx);
  }
}

// ------------- layer 0 scan (grid = 128 x 2 dirs, 1024 thr) -----------------
__global__ __launch_bounds__(1024, 1) void lstm_l0(
    const float* __restrict__ x,
    const unsigned short* __restrict__ pk_f, const unsigned short* __restrict__ pk_b,
    unsigned short* __restrict__ h0fT, unsigned short* __restrict__ h0bT) {
  __shared__ __align__(16) short A_s[2][16][16][8];  // [buf][kg][m16][jj], K=128

  const int tid = threadIdx.x;
  const int lane = tid & 63, w = tid >> 6;       // 16 waves
  const int q = lane >> 4, l16 = lane & 15;
  const int b0 = blockIdx.x * MB;
  const int dir = blockIdx.y;
  const unsigned short* pk = dir ? pk_b : pk_f;
  unsigned short* hT = dir ? h0bT : h0fT;

  for (int i = tid; i < 2 * 16 * 16 * 8; i += 1024) ((short*)A_s)[i] = 0;

  const int mtA = w, mtB = w + 16;
  const bool bvalid = (mtB < NT);
  bf16x8 wfA[4], wfB[4];
#pragma unroll
  for (int kt = 0; kt < 4; ++kt) {
    wfA[kt] = *(const bf16x8*)(pk + ((size_t)(kt * 4 + q) * NP + mtA * 16 + l16) * 8);
    wfB[kt] = *(const bf16x8*)(pk + ((size_t)(kt * 4 + q) * NP + mtB * 16 + l16) * 8);
  }
  float c = 0.f;
  const bool up = (l16 >= 8);
  const int mm = l16 & 7;
  const int j = (up ? mtB : mtA) * 4 + q;
  const bool valid = up ? bvalid : true;
  const int xm = tid / IN_, xe = tid - xm * IN_;              // x loader (tid<40)
  const int sm = tid / 25, sj = (tid - (tid / 25) * 25) * 4;  // h store (tid<200)
  const float* xp = x + ((size_t)(b0 + xm) * Tt + (dir ? Tt - 2 : 1)) * IN_ + xe;
  const int xstride = dir ? -IN_ : IN_;
  unsigned short* hp =
      hT + ((size_t)(dir ? Tt - 1 : 0) * Bsz + b0 + sm) * H + sj;
  const int hstride = dir ? -(Bsz * H) : (Bsz * H);
  __syncthreads();
  if (tid < 16) {  // bias-one col k=105 (kg13,jj1), both bufs
    A_s[0][13][tid][1] = (short)f2bf(1.f);
    A_s[1][13][tid][1] = (short)f2bf(1.f);
  }
  if (tid < MB * IN_) {  // x(t_first) -> buf0, direct f32 read
    int t0 = dir ? (Tt - 1) : 0;
    int k = 100 + xe;
    A_s[0][k >> 3][xm][k & 7] =
        (short)f2bf(x[((size_t)(b0 + xm) * Tt + t0) * IN_ + xe]);
  }
  __syncthreads();

  int p = 0;
  for (int step = 0; step < Tt; ++step) {
    if (step > 0 && tid < 200) {  // coalesced store of h(prev) from buf p
      uint2 hv = *(const uint2*)&A_s[p][sj >> 3][sm][sj & 7];
      *(uint2*)hp = hv;
      hp += hstride;
    }
    float xn = 0.f;
    const bool do_x = (tid < MB * IN_) && (step < Tt - 1);
    if (do_x) { xn = *xp; xp += xstride; }
    bf16x8 hfrag[4];
#pragma unroll
    for (int kt = 0; kt < 4; ++kt) hfrag[kt] = *(const bf16x8*)A_s[p][kt * 4 + q][l16];
    f32x4 accA = (f32x4){0.f, 0.f, 0.f, 0.f};
    f32x4 accB = (f32x4){0.f, 0.f, 0.f, 0.f};
#pragma unroll
    for (int kt = 0; kt < 4; ++kt)
      accA = __builtin_amdgcn_mfma_f32_16x16x32_bf16(wfA[kt], hfrag[kt], accA, 0, 0, 0);
    if (bvalid) {
#pragma unroll
      for (int kt = 0; kt < 4; ++kt)
        accB = __builtin_amdgcn_mfma_f32_16x16x32_bf16(wfB[kt], hfrag[kt], accB, 0, 0, 0);
    }
    float pb0 = partner8(accB[0]), pb1 = partner8(accB[1]);
    float pb2 = partner8(accB[2]), pb3 = partner8(accB[3]);
    float g0 = up ? pb0 : accA[0];
    float g1 = up ? pb1 : accA[1];
    float g2 = up ? pb2 : accA[2];
    float g3 = up ? pb3 : accA[3];
    float cc = sigm(g1) * c + sigm(g0) * tanhf_(g2);
    c = cc;
    float h = sigm(g3) * tanhf_(cc);
    if (valid) A_s[1 - p][j >> 3][mm][j & 7] = (short)f2bf(h);
    if (do_x) {
      int k = 100 + xe;
      A_s[1 - p][k >> 3][xm][k & 7] = (short)f2bf(xn);
    }
    __syncthreads();
    p ^= 1;
  }
  if (tid < 200) *(uint2*)hp = *(const uint2*)&A_s[p][sj >> 3][sm][sj & 7];  // final h
}

// ---- xgT[t*1024+b][400] = [h0f|h0b] @ W_ih_l1f^T + bias (fp16, interleaved) --
__global__ __launch_bounds__(1024, 1) void gemm_xg(
    const unsigned short* __restrict__ h0fT, const unsigned short* __restrict__ h0bT,
    const unsigned short* __restrict__ pkw, __half* __restrict__ xg) {
  __shared__ __align__(16) short B_s[28][64][8];  // K=224 aug (k=200 bias-one)
  const int tid = threadIdx.x;
  const int lane = tid & 63, w = tid >> 6;   // 16 waves
  const int q = lane >> 4, l16 = lane & 15;
  const int r0 = blockIdx.x * 64;            // rows r = t*1024+b
  const size_t base = (size_t)r0 * H;

  for (int i = tid; i < 3 * 64 * 8; i += 1024) {  // kg 25..27: zero + bias-one
    int jj = i & 7, gl = i >> 9;
    ((short*)&B_s[25][0][0])[i] = (short)((gl == 0 && jj == 0) ? f2bf(1.f) : 0);
  }
  for (int idx = tid; idx < 1600; idx += 1024) {  // h0f k=0..99, h0b k=100..199
    int m = idx / 25, j0 = (idx - (idx / 25) * 25) * 4;
    *(uint2*)&B_s[j0 >> 3][m][j0 & 7] = *(const uint2*)(h0fT + base + m * H + j0);
    int k = 100 + j0;
    *(uint2*)&B_s[k >> 3][m][k & 7] = *(const uint2*)(h0bT + base + m * H + j0);
  }

  const int mtA = w, mtB = w + 16;
  const bool bvalid = (mtB < NT);
  bf16x8 wfA[7], wfB[7];
#pragma unroll
  for (int kt = 0; kt < 7; ++kt) {
    wfA[kt] = *(const bf16x8*)(pkw + ((size_t)(kt * 4 + q) * NP + mtA * 16 + l16) * 8);
    wfB[kt] = *(const bf16x8*)(pkw + ((size_t)(kt * 4 + q) * NP + mtB * 16 + l16) * 8);
  }
  const int jA = mtA * 4 + q, jB = mtB * 4 + q;
  __syncthreads();

#pragma unroll
  for (int rg = 0; rg < 4; ++rg) {
    f32x4 accA = (f32x4){0.f, 0.f, 0.f, 0.f};
    f32x4 accB = (f32x4){0.f, 0.f, 0.f, 0.f};
#pragma unroll
    for (int kt = 0; kt < 7; ++kt) {
      bf16x8 hf = *(const bf16x8*)B_s[kt * 4 + q][rg * 16 + l16];
      accA = __builtin_amdgcn_mfma_f32_16x16x32_bf16(wfA[kt], hf, accA, 0, 0, 0);
      if (bvalid)
        accB = __builtin_amdgcn_mfma_f32_16x16x32_bf16(wfB[kt], hf, accB, 0, 0, 0);
    }
    const size_t row = (size_t)(r0 + rg * 16 + l16);
    {
      __half2 h01 = __floats2half2_rn(accA[0], accA[1]);
      __half2 h23 = __floats2half2_rn(accA[2], accA[3]);
      uint2 st; *(__half2*)&st.x = h01; *(__half2*)&st.y = h23;
      *(uint2*)(xg + row * G + 4 * jA) = st;
    }
    if (bvalid) {
      __half2 h01 = __floats2half2_rn(accB[0], accB[1]);
      __half2 h23 = __floats2half2_rn(accB[2], accB[3]);
      uint2 st; *(__half2*)&st.x = h01; *(__half2*)&st.y = h23;
      *(uint2*)(xg + row * G + 4 * jB) = st;
    }
  }
}

// ---- layer 1: MB1=4, 256 blocks, dense 4 tiles/wave (waves 0..6 busy) ------
__global__ __launch_bounds__(1024, 1) void lstm_l1(
    const unsigned short* __restrict__ h0fT, const unsigned short* __restrict__ h0bT,
    const unsigned short* __restrict__ pk_hh, const unsigned short* __restrict__ pk1b,
    const __half* __restrict__ xg,
    const float* __restrict__ fc_w, const float* __restrict__ fc_b,
    float* __restrict__ out) {
  __shared__ __align__(16) short A_s[2][16][16][8];      // h1, K=128 (m 0..3 used)
  __shared__ __align__(16) short A2_s[28][16][8];        // epilogue [h0|1] K=224
  __shared__ float hf_s[MB1][H];
  __shared__ float hb_s[MB1][H];
  __shared__ float fcw_s[3 * D1];
  __shared__ float fcb_s[3];
  __shared__ float logit_s[MB1][3];

  const int tid = threadIdx.x;
  const int lane = tid & 63, w = tid >> 6;   // 16 waves
  const int q = lane >> 4, l16 = lane & 15;
  const int b0 = blockIdx.x * MB1;           // 256 blocks
  const uint2* xg2 = (const uint2*)xg;       // 100 uint2 per (t,b) row

  for (int i = tid; i < 2 * 16 * 16 * 8; i += 1024) ((short*)A_s)[i] = 0;
  for (int i = tid; i < 25 * 16 * 8; i += 1024) ((short*)A2_s)[i] = 0;  // kg 0..24
  for (int i = tid; i < 3 * 16 * 8; i += 1024) {  // A2 kg25..27 zero + bias-one
    int jj = i & 7, gl = i >> 7;
    ((short*)&A2_s[25][0][0])[i] = (short)((gl == 0 && jj == 0) ? f2bf(1.f) : 0);
  }
  for (int i = tid; i < 3 * D1; i += 1024) fcw_s[i] = fc_w[i];
  if (tid < 3) fcb_s[tid] = fc_b[tid];

  const bool busy = (w < 7);                 // waves 0..6 own tiles 4w..4w+3
  const int m = l16 & 3, g16 = l16 >> 2;
  const int myMt = w * 4 + g16;
  const int jme = myMt * 4 + q;              // my element's j (>=100 invalid)
  const bool evalid = busy && (myMt < NT);
  int mts[4]; bool tv[4];
  bf16x8 wf[4][4];
  if (busy) {
#pragma unroll
    for (int i = 0; i < 4; ++i) {
      int mt = w * 4 + i; mts[i] = mt; tv[i] = (mt < NT);
#pragma unroll
      for (int kt = 0; kt < 4; ++kt)
        wf[i][kt] = *(const bf16x8*)(pk_hh + ((size_t)(kt * 4 + q) * NP + mt * 16 + l16) * 8);
    }
  }
  float c = 0.f;
  // per-lane own-element xg, running pointer (+102400 uint2 per t);
  // invalid jme (<=111) reads <=96B past the row — lands in ws, unused.
  const uint2* xgp = xg2 + (size_t)(b0 + m) * 100 + jme;
  uint2 xgCur = {0, 0};
  if (busy) { xgCur = *xgp; xgp += Bsz * 100; }
  __syncthreads();

  int p = 0;
  for (int t = 0; t < Tt; ++t) {
    if (busy) {
      uint2 xgNxt = xgCur;
      if (t < Tt - 1) { xgNxt = *xgp; xgp += Bsz * 100; }
      bf16x8 hfrag[4];
#pragma unroll
      for (int kt = 0; kt < 4; ++kt) hfrag[kt] = *(const bf16x8*)A_s[p][kt * 4 + q][l16];
      f32x4 acc[4];
#pragma unroll
      for (int i = 0; i < 4; ++i) {
        acc[i] = (f32x4){0.f, 0.f, 0.f, 0.f};
        if (!tv[i]) continue;
#pragma unroll
        for (int kt = 0; kt < 4; ++kt)
          acc[i] = __builtin_amdgcn_mfma_f32_16x16x32_bf16(wf[i][kt], hfrag[kt], acc[i], 0, 0, 0);
      }
      // spread: all lanes swizzle unconditionally (src lane = same q, l16=m),
      // then 2-level select by g16; add own xg.
      float2 x01 = __half22float2(*(const __half2*)&xgCur.x);
      float2 x23 = __half22float2(*(const __half2*)&xgCur.y);
      float xr[4] = {x01.x, x01.y, x23.x, x23.y};
      float gr[4];
#pragma unroll
      for (int r = 0; r < 4; ++r) {
        float v0 = partner4(acc[0][r]);
        float v1 = partner4(acc[1][r]);
        float v2 = partner4(acc[2][r]);
        float v3 = partner4(acc[3][r]);
        float lo = (g16 & 1) ? v1 : v0;
        float hi = (g16 & 1) ? v3 : v2;
        gr[r] = ((g16 & 2) ? hi : lo) + xr[r];
      }
      float cc = sigm(gr[1]) * c + sigm(gr[0]) * tanhf_(gr[2]);
      c = cc;
      float h = sigm(gr[3]) * tanhf_(cc);
      if (evalid) {
        A_s[1 - p][jme >> 3][m][jme & 7] = (short)f2bf(h);
        if (t == Tt - 1) hf_s[m][jme] = h;
      }
      xgCur = xgNxt;
    }
    __syncthreads();
    p ^= 1;
  }

  // ---- layer-1 backward single step at t=T-1 (h=c=0) ----
  {
    const size_t base = ((size_t)(Tt - 1) * Bsz + b0) * H;
    if (tid < 100) {  // stage rows m=0..3 only (this block's batch)
      int m2 = tid / 25, j0 = (tid - (tid / 25) * 25) * 4;
      *(uint2*)&A2_s[j0 >> 3][m2][j0 & 7] = *(const uint2*)(h0fT + base + m2 * H + j0);
      int k = 100 + j0;
      *(uint2*)&A2_s[k >> 3][m2][k & 7] = *(const uint2*)(h0bT + base + m2 * H + j0);
    }
  }
  __syncthreads();
  if (busy) {
    f32x4 acc[4];
#pragma unroll
    for (int i = 0; i < 4; ++i) acc[i] = (f32x4){0.f, 0.f, 0.f, 0.f};
#pragma unroll
    for (int kt = 0; kt < 7; ++kt) {
      bf16x8 hf = *(const bf16x8*)A2_s[kt * 4 + q][l16];
#pragma unroll
      for (int i = 0; i < 4; ++i) {
        if (!tv[i]) continue;
        bf16x8 wfb = *(const bf16x8*)(pk1b + ((size_t)(kt * 4 + q) * NP + mts[i] * 16 + l16) * 8);
        acc[i] = __builtin_amdgcn_mfma_f32_16x16x32_bf16(wfb, hf, acc[i], 0, 0, 0);
      }
    }
    float gr[4];
#pragma unroll
    for (int r = 0; r < 4; ++r) {
      float v0 = partner4(acc[0][r]);
      float v1 = partner4(acc[1][r]);
      float v2 = partner4(acc[2][r]);
      float v3 = partner4(acc[3][r]);
      float lo = (g16 & 1) ? v1 : v0;
      float hi = (g16 & 1) ? v3 : v2;
      gr[r] = (g16 & 2) ? hi : lo;
    }
    float cc = sigm(gr[0]) * tanhf_(gr[2]);   // c_prev = 0
    if (evalid) hb_s[m][jme] = sigm(gr[3]) * tanhf_(cc);
  }
  __syncthreads();

  // ---- FC (3x200) + softmax ----
  if (tid < MB1 * 3) {
    int mr = tid / 3, cls = tid - mr * 3;
    float s = fcb_s[cls];
    for (int jj = 0; jj < H; ++jj) s += fcw_s[cls * D1 + jj] * hf_s[mr][jj];
    for (int jj = 0; jj < H; ++jj) s += fcw_s[cls * D1 + H + jj] * hb_s[mr][jj];
    logit_s[mr][cls] = s;
  }
  __syncthreads();
  if (tid < MB1) {
    float a = logit_s[tid][0], b = logit_s[tid][1], cc = logit_s[tid][2];
    float mx = fmaxf(a, fmaxf(b, cc));
    float e0 = __expf(a - mx), e1 = __expf(b - mx), e2 = __expf(cc - mx);
    float inv = 1.f / (e0 + e1 + e2);
    out[(b0 + tid) * 3 + 0] = e0 * inv;
    out[(b0 + tid) * 3 + 1] = e1 * inv;
    out[(b0 + tid) * 3 + 2] = e2 * inv;
  }
}

extern "C" void kernel_launch(void* const* d_in, const int* in_sizes, int n_in,
                              void* d_out, int out_size, void* d_ws, size_t ws_size,
                              hipStream_t stream) {
  const float* x        = (const float*)d_in[0];
  const float* w_ih_l0f = (const float*)d_in[1];
  const float* w_hh_l0f = (const float*)d_in[2];
  const float* b_ih_l0f = (const float*)d_in[3];
  const float* b_hh_l0f = (const float*)d_in[4];
  const float* w_ih_l0b = (const float*)d_in[5];
  const float* w_hh_l0b = (const float*)d_in[6];
  const float* b_ih_l0b = (const float*)d_in[7];
  const float* b_hh_l0b = (const float*)d_in[8];
  const float* w_ih_l1f = (const float*)d_in[9];
  const float* w_hh_l1f = (const float*)d_in[10];
  const float* b_ih_l1f = (const float*)d_in[11];
  const float* b_hh_l1f = (const float*)d_in[12];
  const float* w_ih_l1b = (const float*)d_in[13];
  // d_in[14] = w_hh_l1b unused (reverse dir at t=T-1 has h=0)
  const float* b_ih_l1b = (const float*)d_in[15];
  const float* b_hh_l1b = (const float*)d_in[16];
  const float* fc_w     = (const float*)d_in[17];
  const float* fc_b     = (const float*)d_in[18];

  unsigned short* h0fT = (unsigned short*)d_ws;
  unsigned short* h0bT = h0fT + (size_t)Tt * Bsz * H;
  __half* xgT          = (__half*)(h0bT + (size_t)Tt * Bsz * H);
  unsigned short* pk0f = (unsigned short*)(xgT + (size_t)Tt * Bsz * G);
  unsigned short* pk0b = pk0f + 16 * NP * 8;
  unsigned short* pkhh = pk0b + 16 * NP * 8;
  unsigned short* pkxg = pkhh + 16 * NP * 8;
  unsigned short* pk1b = pkxg + 28 * NP * 8;

  pack_all<<<dim3(448, 5), 256, 0, stream>>>(
      w_hh_l0f, w_ih_l0f, b_ih_l0f, b_hh_l0f,
      w_hh_l0b, w_ih_l0b, b_ih_l0b, b_hh_l0b,
      w_hh_l1f, b_ih_l1f, b_hh_l1f,
      w_ih_l1f, w_ih_l1b, b_ih_l1b, b_hh_l1b,
      pk0f, pk0b, pkhh, pkxg, pk1b);

  lstm_l0<<<dim3(Bsz / MB, 2), 1024, 0, stream>>>(x, pk0f, pk0b, h0fT, h0bT);
  gemm_xg<<<(Bsz * Tt) / 64, 1024, 0, stream>>>(h0fT, h0bT, pkxg, xgT);
  lstm_l1<<<Bsz / MB1, 1024, 0, stream>>>(h0fT, h0bT, pkhh, pk1b, xgT,
                                          fc_w, fc_b, (float*)d_out);
}